// Round 15
// baseline (471.898 us; speedup 1.0000x reference)
//
#include <hip/hip_runtime.h>
#include <hip/hip_bf16.h>

// InteractionBlock: per-edge radial MLP (8->64->64->768) + tensor product
// contraction + scatter-sum + self-interaction + batchnorm epilogue.
// Round 26: occupancy via LDS diet (low-risk). r25 re-anchor passed at
// 456us, confirming r23/r24 failures were their levers; common thread:
// bf16x8 tuple spills at/over the forced-128 cap miscompile (r15/r23/r24)
// -- register-pressure-raising direction quarantined. Edge is stall-
// dominated (VALU 28.8%, Mfma 5.4%, HBM 12.6%, Occ 17.4% ~ 1.4 w/SIMD;
// per-wave wall ~160K cy vs ~35K modeled work). Most robust lever: more
// resident waves. LDS binds at 37376B/block = 4 blocks/CU. Fix: vxl
// (f*sh0 table) stored as bf16 u16 (6144->3072B/wave): block 31232B ->
// 5 blocks/CU = 10 waves/CU (+25%), zero reg-pressure delta, ~120 extra
// VALU inst (f2bf/bflo), precision ~2^-8 on one vector-output term
// (headroom 0.0625 vs 0.24375). All else byte-identical to r25.

#define N_NODES_C 50000
#define N_EDGES_C 300000
#define ALPHA_C 0.20412414523193154f   // 1/sqrt(24)
#define INV_SQRT3_C 0.5773502691896258f
#define BN_EPS_C 1e-5f

typedef unsigned int u32;
typedef unsigned long long u64;
typedef unsigned short u16;
typedef __attribute__((ext_vector_type(8))) short bf16x8;
typedef __attribute__((ext_vector_type(4))) float f32x4;

// workspace layout (float offsets)
#define OFF_STATS 0u            // 40
#define OFF_FLAG  48u           // u32 dtype flag
#define OFF_W3T   64u           // 49152 floats: frag-packed W3 bf16 hi + lo
#define OFF_W1T   49216u        // 512
#define OFF_B1    49728u        // 64
#define OFF_W2T   49792u        // 4096
#define OFF_B2    53888u        // 64
#define OFF_B3    53952u        // 768 (chunk-permuted)
#define OFF_SI0   54720u        // 256
#define OFF_SI1   54976u        // 64
#define OFF_AGG   55040u        // 50000*48 = 2,400,000 (svb in-place)
#define REQ_WS_BYTES ((size_t)(55040u + 2400000u) * 4u)
// sorted-path extras
#define OFF_SPART   2455040u    // 782*40 floats (stats partials)
#define OFF_START   2505040u    // 50001 ints
#define OFF_CURSOR  2555044u    // 50000 ints (zero-init; ends as deg)
#define OFF_POS     2605044u    // 300000 ints (slot = start[dst]+rank, precomputed)
#define OFF_MSG     2905044u    // 300000*48 floats (16B aligned)
#define REQ2_WS_BYTES ((size_t)(2905044u + 14400000u) * 4u)   // ~69.2 MB

#define GATHER_BLOCKS ((N_NODES_C + 63) / 64)   // 782

__device__ __forceinline__ float bflo(u32 u){ union{u32 i; float f;} c; c.i = u<<16; return c.f; }
__device__ __forceinline__ float bfhi(u32 u){ union{u32 i; float f;} c; c.i = u & 0xffff0000u; return c.f; }
__device__ __forceinline__ float b2f(__hip_bfloat16 b){ return (float)b; }
__device__ __forceinline__ u16 f2bf(float f){
    union{float f; u32 i;} c; c.f = f;
    u32 r = c.i + 0x7fffu + ((c.i>>16)&1u);
    return (u16)(r>>16);
}
__device__ __forceinline__ float sigmoidf_(float x){ return 1.0f/(1.0f+__expf(-x)); }
__device__ __forceinline__ float siluf_(float x){ return x*sigmoidf_(x); }
__device__ __forceinline__ float rdv(const void* p, int idx, bool fm){
    return fm ? ((const float*)p)[idx] : b2f(((const __hip_bfloat16*)p)[idx]);
}
// chunk/col -> original tp_w column (output-major repack)
__device__ __forceinline__ int w3col(int cc, int c){
    int kk = (c >= 24) ? (c - 24) : c;
    int hb = (c >= 24) ? 1 : 0;
    if (cc < 12){
        int w = 2*cc + hb;
        return (kk < 16) ? (kk*24 + w) : (384 + (kk-16)*24 + w);
    } else {
        int w = 2*(cc-12) + hb;
        return (kk < 16) ? (576 + kk*8 + w) : (704 + (kk-16)*8 + w);
    }
}
// per-wave LDS fence: LDS is wave-private; lgkmcnt(0) orders ds_write ->
// ds_read within the wave. vmcnt NOT drained: global prefetch loads stay
// in flight across it. No sched_barrier (rule-18 hazard is asm-ds_read-only).
__device__ __forceinline__ void wave_fence(){
    asm volatile("s_waitcnt lgkmcnt(0)" ::: "memory");
}

__global__ __launch_bounds__(256) void fill_kernel(u32* __restrict__ p, int n, u32 v){
    int i = blockIdx.x*256 + threadIdx.x;
    if (i < n) p[i] = v;
}

// ---------------- prep (detect folded in; W3T + b3 chunk-permuted) ----------------
__global__ __launch_bounds__(256) void prep_kernel(
    const void* __restrict__ nf,
    const void* __restrict__ W1, const void* __restrict__ b1,
    const void* __restrict__ W2, const void* __restrict__ b2,
    const void* __restrict__ W3, const void* __restrict__ b3,
    const void* __restrict__ si0, const void* __restrict__ si1,
    float* __restrict__ ws)
{
    __shared__ u32 fmsh;
    {
        const int t = threadIdx.x;
        if (t < 64){
            u32 w = ((const u32*)nf)[t];
            int bad = 0;
            u32 lo = w & 0xffffu, hi = w >> 16;
            u32 elo = (lo >> 7) & 0xffu, ehi = (hi >> 7) & 0xffu;
            if (!(lo == 0u || (elo >= 90u && elo <= 140u))) bad++;
            if (!(hi == 0u || (ehi >= 90u && ehi <= 140u))) bad++;
            for (int off=32; off; off>>=1) bad += __shfl_down(bad, off);
            if (t == 0) fmsh = (bad >= 8) ? 1u : 0u;
        }
        __syncthreads();
    }
    const bool fm = fmsh != 0u;
    if (blockIdx.x == 0 && threadIdx.x == 0) ((u32*)(ws + OFF_FLAG))[0] = fm ? 1u : 0u;

    int i = blockIdx.x*256 + threadIdx.x;
    if (i < 49152){
        int j = i & 7, lane = (i>>3)&63, kh = (i>>9)&1, nt = i>>10;
        int n = lane & 15, qd = lane >> 4;
        int k = kh*32 + qd*8 + j;
        int cc = nt/3, c = (nt%3)*16 + n;
        int col = w3col(cc, c);
        float v = rdv(W3, k*768 + col, fm);
        u16 hv = f2bf(v);
        float hf = bflo((u32)hv);
        u16 lv = f2bf(v - hf);
        u16* BH = (u16*)(ws + OFF_W3T);
        BH[i] = hv;
        BH[49152 + i] = lv;
        return;
    }
    i -= 49152;
    if (i < 512){ int j=i>>3, t=i&7; ws[OFF_W1T+i] = rdv(W1, t*64+j, fm); return; }
    i -= 512;
    if (i < 64){ ws[OFF_B1+i] = rdv(b1, i, fm); return; }
    i -= 64;
    if (i < 4096){ int j=i>>6, k=i&63; ws[OFF_W2T+i] = rdv(W2, k*64+j, fm); return; }
    i -= 4096;
    if (i < 64){ ws[OFF_B2+i] = rdv(b2, i, fm); return; }
    i -= 64;
    if (i < 768){
        int cc = i/48, c = i%48;
        ws[OFF_B3+i] = rdv(b3, w3col(cc, c), fm);
        return;
    }
    i -= 768;
    if (i < 256){ int w=i>>4, u=i&15; ws[OFF_SI0+i] = rdv(si0, u*16+w, fm)*0.25f; return; }
    i -= 256;
    if (i < 64){ int w=i>>3, u=i&7; ws[OFF_SI1+i] = rdv(si1, u*8+w, fm)*0.35355339059327373f; return; }
}

// ---------------- sort: rank (single atomic pass) + scan + pos ----------------
__global__ __launch_bounds__(256) void rank_kernel(const int* __restrict__ dst,
                                                   int* __restrict__ cursor,
                                                   int* __restrict__ rank){
    int i = blockIdx.x*256 + threadIdx.x;
    if (i < N_EDGES_C){
        rank[i] = atomicAdd(&cursor[dst[i]], 1);   // cursor ends as deg[]
    }
}

__global__ __launch_bounds__(1024) void scan_kernel(const int* __restrict__ deg,
                                                    int* __restrict__ start){
    __shared__ int buf[2][1024];
    const int t = threadIdx.x;
    const int c0 = t*49;
    int local = 0;
    #pragma unroll 1
    for (int i=0;i<49;i++){ int idx=c0+i; if (idx<N_NODES_C) local += deg[idx]; }
    buf[0][t] = local;
    __syncthreads();
    int src=0;
    for (int off=1; off<1024; off<<=1){
        int v = buf[src][t];
        if (t>=off) v += buf[src][t-off];
        buf[src^1][t]=v;
        src^=1;
        __syncthreads();
    }
    int off = (t==0)?0:buf[src][t-1];
    #pragma unroll 1
    for (int i=0;i<49;i++){
        int idx=c0+i;
        if (idx<N_NODES_C){ start[idx]=off; off+=deg[idx]; }
    }
    if (t==0) start[N_NODES_C]=buf[src][1023];
}

// pos[e] = start[dst[e]] + rank[e]  (in-place over rank)
__global__ __launch_bounds__(256) void pos_kernel(const int* __restrict__ dst,
                                                  const int* __restrict__ start,
                                                  int* __restrict__ rankpos){
    int i = blockIdx.x*256 + threadIdx.x;
    if (i < N_EDGES_C){
        rankpos[i] = start[dst[i]] + rankpos[i];
    }
}

// ---------------- edge kernel (output-major chunks; bf16 vxl table) ----------------
template<bool SORTED>
__global__ __launch_bounds__(128, 2) void edge_kernel_t(
    const void* __restrict__ nfv,
    const void* __restrict__ eshv,
    const void* __restrict__ ebv,
    const int* __restrict__ eidx,
    const float* __restrict__ ws,
    const int* __restrict__ pos,
    float* __restrict__ outbuf)      // SORTED: msg[300K][48] ; else: agg[50K][48]
{
    // Per-wave slice: 12544B tpb/h2 overlay + 3072B vxl16 = 15616B.
    // Block LDS = 31232B -> 5 blocks/CU (was 4) = 10 waves/CU ceiling.
    __shared__ __align__(16) char uni[2][15616];
    const int wv   = threadIdx.x >> 6;
    const int lane = threadIdx.x & 63;
    u16   (*h2hi)[72] = (u16 (*)[72])uni[wv];   // [64][72]
    float (*tpb)[49]  = (float (*)[49])uni[wv]; // [64][49]
    u16   (*vxl16)[64]= (u16 (*)[64])(uni[wv] + 12544); // [24][64] bf16

    const bool fm = ((const u32*)(ws + OFF_FLAG))[0] != 0u;
    const int m    = lane & 15;
    const int quad = lane >> 4;
    const int e    = blockIdx.x*128 + threadIdx.x;
    const bool act = e < N_EDGES_C;
    const int slot = (SORTED && act) ? pos[e] : 0;   // early, coalesced
    const int src  = act ? eidx[e] : 0;
    const int dstn = (!SORTED && act) ? eidx[N_EDGES_C + e] : 0;

    // ---- edge-local inputs (esh, basis); f[40] deferred until after MLP2 ----
    float sh0=0.f, sh1x=0.f, sh1y=0.f, sh1z=0.f;
    float bas[8];
    #pragma unroll
    for (int i=0;i<8;i++) bas[i]=0.f;
    if (act){
        if (!fm){
            const u32* p = (const u32*)((const __hip_bfloat16*)eshv + (size_t)e*4);
            u32 a = p[0], b = p[1];
            sh0 = bflo(a); sh1x = bfhi(a); sh1y = bflo(b); sh1z = bfhi(b);
            uint4 r = *(const uint4*)((const __hip_bfloat16*)ebv + (size_t)e*8);
            bas[0]=bflo(r.x); bas[1]=bfhi(r.x); bas[2]=bflo(r.y); bas[3]=bfhi(r.y);
            bas[4]=bflo(r.z); bas[5]=bfhi(r.z); bas[6]=bflo(r.w); bas[7]=bfhi(r.w);
        } else {
            float4 r = *(const float4*)((const float*)eshv + (size_t)e*4);
            sh0 = r.x; sh1x = r.y; sh1y = r.z; sh1z = r.w;
            const float4* qb = (const float4*)((const float*)ebv + (size_t)e*8);
            float4 t0 = qb[0], t1 = qb[1];
            bas[0]=t0.x; bas[1]=t0.y; bas[2]=t0.z; bas[3]=t0.w;
            bas[4]=t1.x; bas[5]=t1.y; bas[6]=t1.z; bas[7]=t1.w;
        }
    }

    // ---- MLP1 ----
    const float* W1T = ws + OFF_W1T;
    const float* b1f = ws + OFF_B1;
    float h1[64];
    #pragma unroll
    for (int j=0;j<64;j++){
        const float* w = W1T + j*8;
        float t0 = b1f[j] + bas[0]*w[0] + bas[4]*w[4];
        float t1 = bas[1]*w[1] + bas[5]*w[5];
        float t2 = bas[2]*w[2] + bas[6]*w[6];
        float t3 = bas[3]*w[3] + bas[7]*w[7];
        h1[j] = siluf_((t0+t1)+(t2+t3));
    }

    // ---- MLP2 -> bf16 h2 rows in LDS (paired u32 writes) ----
    const float* W2T = ws + OFF_W2T;
    const float* bb2 = ws + OFF_B2;
    #pragma unroll 1
    for (int j=0;j<64;j+=2){
        const float* w0 = W2T + j*64;
        const float* w1 = w0 + 64;
        float a0=bb2[j],   a1=0.f, a2=0.f, a3=0.f;
        float c0=bb2[j+1], c1=0.f, c2=0.f, c3=0.f;
        #pragma unroll
        for (int k=0;k<64;k+=4){
            a0 += h1[k]*w0[k];     a1 += h1[k+1]*w0[k+1];
            a2 += h1[k+2]*w0[k+2]; a3 += h1[k+3]*w0[k+3];
            c0 += h1[k]*w1[k];     c1 += h1[k+1]*w1[k+1];
            c2 += h1[k+2]*w1[k+2]; c3 += h1[k+3]*w1[k+3];
        }
        u32 pk = (u32)f2bf(siluf_((a0+a1)+(a2+a3)))
               | ((u32)f2bf(siluf_((c0+c1)+(c2+c3)))<<16);
        *(u32*)&h2hi[lane][j] = pk;
    }
    wave_fence();

    // ---- f[40] load NOW (dead across MLP1/2 -> no spill pressure there);
    //      global latency overlaps the Afr LDS reads below ----
    float f[40];
    #pragma unroll
    for (int i=0;i<40;i++) f[i]=0.f;
    if (act){
        if (!fm){
            const uint4* qq = (const uint4*)((const __hip_bfloat16*)nfv + (size_t)src*40);
            #pragma unroll
            for (int i=0;i<5;i++){
                uint4 r = qq[i];
                f[i*8+0]=bflo(r.x); f[i*8+1]=bfhi(r.x);
                f[i*8+2]=bflo(r.y); f[i*8+3]=bfhi(r.y);
                f[i*8+4]=bflo(r.z); f[i*8+5]=bfhi(r.z);
                f[i*8+6]=bflo(r.w); f[i*8+7]=bfhi(r.w);
            }
        } else {
            const float4* qq = (const float4*)((const float*)nfv + (size_t)src*40);
            #pragma unroll
            for (int i=0;i<10;i++){
                float4 t = qq[i];
                f[i*4+0]=t.x; f[i*4+1]=t.y; f[i*4+2]=t.z; f[i*4+3]=t.w;
            }
        }
    }

    // ---- A fragments (consume all of h2 into registers) ----
    bf16x8 Afr[4][2];
    #pragma unroll
    for (int g=0;g<4;g++){
        Afr[g][0] = *(const bf16x8*)&h2hi[g*16+m][quad*8];
        Afr[g][1] = *(const bf16x8*)&h2hi[g*16+m][32 + quad*8];
    }
    wave_fence();   // h2 region now dead -> tpb may overlay

    // ---- coefficients: dvv in regs; vx table -> per-wave LDS as bf16 ----
    float dvv[8];
    #pragma unroll
    for (int u=0;u<8;u++)
        dvv[u] = (f[16+u*3]*sh1x + f[17+u*3]*sh1y + f[18+u*3]*sh1z)*INV_SQRT3_C;
    #pragma unroll
    for (int j=0;j<24;j++) vxl16[j][lane] = f2bf(f[16+j]*sh0);
    // (vxl16 ds_writes drain at the first in-loop wave_fence before any read)

    const short* BH = (const short*)(ws + OFF_W3T);
    const float* b3f = ws + OFF_B3;

    // B = W3 bf16 hi only: Bc[6] = 24 VGPRs, 2 MFMA per (ntl,g).
    auto loadB = [&](bf16x8* dst2, int cc2){
        #pragma unroll
        for (int ntl=0; ntl<3; ntl++){
            const int nt = cc2*3 + ntl;
            dst2[ntl*2+0] = *(const bf16x8*)(BH + ((nt*2+0)*64 + lane)*8);
            dst2[ntl*2+1] = *(const bf16x8*)(BH + ((nt*2+1)*64 + lane)*8);
        }
    };

    bf16x8 Bc[6];
    loadB(Bc, 0);

    float* const mp = SORTED ? (outbuf + (size_t)slot*48)
                             : (outbuf + (size_t)dstn*48);

    #pragma unroll 1
    for (int cc=0; cc<16; cc++){
        // ---- MFMA phase: tpb[row][c] = h2 @ W3[:, w3col(cc,c)] ----
        #pragma unroll
        for (int ntl=0; ntl<3; ntl++){
            #pragma unroll
            for (int g=0; g<4; g++){
                f32x4 acc = {0.f,0.f,0.f,0.f};
                acc = __builtin_amdgcn_mfma_f32_16x16x32_bf16(Afr[g][0], Bc[ntl*2+0], acc, 0,0,0);
                acc = __builtin_amdgcn_mfma_f32_16x16x32_bf16(Afr[g][1], Bc[ntl*2+1], acc, 0,0,0);
                #pragma unroll
                for (int r=0;r<4;r++) tpb[g*16+quad*4+r][ntl*16+m] = acc[r];
            }
        }
        if (cc < 15) loadB(Bc, cc+1);   // stays in flight across lgkm fence
        wave_fence();

        const float* b3c = b3f + cc*48;   // wave-uniform values
        if (cc < 12){
            // ---- s-output pair (2cc, 2cc+1), finished this chunk ----
            float sa0=0.f, sa1=0.f, da0=0.f, da1=0.f;
            #pragma unroll
            for (int k=0;k<16;k++){
                sa0 += f[k]*(tpb[lane][k]    + b3c[k]);
                sa1 += f[k]*(tpb[lane][24+k] + b3c[24+k]);
            }
            #pragma unroll
            for (int k=0;k<8;k++){
                da0 += dvv[k]*(tpb[lane][16+k] + b3c[16+k]);
                da1 += dvv[k]*(tpb[lane][40+k] + b3c[40+k]);
            }
            float o0 = (sh0*sa0 + da0)*ALPHA_C;
            float o1 = (sh0*sa1 + da1)*ALPHA_C;
            if (act){
                if (SORTED){
                    *(float2*)(mp + 2*cc) = make_float2(o0, o1);
                } else {
                    atomicAdd(mp + 2*cc,     o0);
                    atomicAdd(mp + 2*cc + 1, o1);
                }
            }
        } else {
            // ---- vector-output pair (w0, w0+1), finished this chunk ----
            const int w0 = 2*(cc-12);
            float t0=0.f, t1=0.f;
            float a00=0.f,a01=0.f,a02=0.f, a10=0.f,a11=0.f,a12=0.f;
            #pragma unroll
            for (int k=0;k<16;k++){
                t0 += f[k]*(tpb[lane][k]    + b3c[k]);
                t1 += f[k]*(tpb[lane][24+k] + b3c[24+k]);
            }
            #pragma unroll
            for (int k=0;k<8;k++){
                float v0 = tpb[lane][16+k] + b3c[16+k];
                float v1 = tpb[lane][40+k] + b3c[40+k];
                float x0 = bflo((u32)vxl16[k*3+0][lane]);
                float x1 = bflo((u32)vxl16[k*3+1][lane]);
                float x2 = bflo((u32)vxl16[k*3+2][lane]);
                a00 += x0*v0; a01 += x1*v0; a02 += x2*v0;
                a10 += x0*v1; a11 += x1*v1; a12 += x2*v1;
            }
            float o0 = (t0*sh1x + a00)*ALPHA_C;
            float o1 = (t0*sh1y + a01)*ALPHA_C;
            float o2 = (t0*sh1z + a02)*ALPHA_C;
            float o3 = (t1*sh1x + a10)*ALPHA_C;
            float o4 = (t1*sh1y + a11)*ALPHA_C;
            float o5 = (t1*sh1z + a12)*ALPHA_C;
            if (act){
                float* vp = mp + 24 + w0*3;
                if (SORTED){
                    *(float2*)(vp + 0) = make_float2(o0, o1);
                    *(float2*)(vp + 2) = make_float2(o2, o3);
                    *(float2*)(vp + 4) = make_float2(o4, o5);
                } else {
                    atomicAdd(vp+0, o0); atomicAdd(vp+1, o1); atomicAdd(vp+2, o2);
                    atomicAdd(vp+3, o3); atomicAdd(vp+4, o4); atomicAdd(vp+5, o5);
                }
            }
        }
        wave_fence();   // tpb/vxl reads done before next iteration's tpb stores
    }
}

// ---------------- sorted-path node kernel: 8 lanes/node gather + epilogue ----------------
// stats: per-block partial -> spart[bid*40..] (plain stores, no atomics).
__global__ __launch_bounds__(512) void gather_node_kernel(
    const float* __restrict__ ws,
    const float* __restrict__ msg,
    const int* __restrict__ start,
    float* __restrict__ svb,
    float* __restrict__ spart)
{
    __shared__ __align__(16) float aggL[64][52];
    const float* si0T = ws + OFF_SI0;
    const float* si1T = ws + OFF_SI1;
    const int tid = threadIdx.x;
    const int nb = blockIdx.x*64;
    {
        const int sub  = tid & 3;        // 4 subs/node, 12 floats each
        const int rsp  = (tid >> 2) & 1; // row parity split
        const int slot = tid >> 3;       // node slot 0..63
        const int n = nb + slot;
        float a[12], b[12];
        #pragma unroll
        for (int i=0;i<12;i++){ a[i]=0.f; b[i]=0.f; }
        if (n < N_NODES_C){
            const int s = start[n], en = start[n+1];
            #pragma unroll 1
            for (int r = s + rsp; r < en; r += 4){
                const float4* mp = (const float4*)(msg + (size_t)r*48) + sub*3;
                float4 t0=mp[0], t1=mp[1], t2=mp[2];
                const int r2 = r + 2;
                if (r2 < en){
                    const float4* mq = (const float4*)(msg + (size_t)r2*48) + sub*3;
                    float4 u0=mq[0], u1=mq[1], u2=mq[2];
                    b[0]+=u0.x; b[1]+=u0.y; b[2]+=u0.z; b[3]+=u0.w;
                    b[4]+=u1.x; b[5]+=u1.y; b[6]+=u1.z; b[7]+=u1.w;
                    b[8]+=u2.x; b[9]+=u2.y; b[10]+=u2.z; b[11]+=u2.w;
                }
                a[0]+=t0.x; a[1]+=t0.y; a[2]+=t0.z; a[3]+=t0.w;
                a[4]+=t1.x; a[5]+=t1.y; a[6]+=t1.z; a[7]+=t1.w;
                a[8]+=t2.x; a[9]+=t2.y; a[10]+=t2.z; a[11]+=t2.w;
            }
        }
        #pragma unroll
        for (int i=0;i<12;i++) a[i] += b[i];
        #pragma unroll
        for (int i=0;i<12;i++) a[i] += __shfl_xor(a[i], 4);
        if (rsp == 0){
            float4* dp = (float4*)&aggL[slot][sub*12];
            dp[0]=make_float4(a[0],a[1],a[2],a[3]);
            dp[1]=make_float4(a[4],a[5],a[6],a[7]);
            dp[2]=make_float4(a[8],a[9],a[10],a[11]);
        }
    }
    __syncthreads();
    if (tid >= 64) return;      // epilogue: one wave, one node per lane
    const int n = nb + tid;
    const bool act = n < N_NODES_C;

    float a[48];
    {
        const float4* p = (const float4*)&aggL[tid][0];
        #pragma unroll
        for (int q=0;q<12;q++){ float4 r=p[q]; a[q*4]=r.x; a[q*4+1]=r.y; a[q*4+2]=r.z; a[q*4+3]=r.w; }
    }
    float spre[16];
    #pragma unroll
    for (int u=0;u<16;u++) spre[u]=siluf_(a[u]);
    float v[24];
    #pragma unroll
    for (int u=0;u<8;u++){
        float g = sigmoidf_(a[16+u]);
        v[u*3+0]=a[24+u*3+0]*g; v[u*3+1]=a[24+u*3+1]*g; v[u*3+2]=a[24+u*3+2]*g;
    }
    float so[16];
    #pragma unroll
    for (int w=0;w<16;w++){
        const float* c = si0T + w*16;
        float t0=0.f,t1=0.f,t2=0.f,t3=0.f;
        #pragma unroll
        for (int u=0;u<16;u+=4){ t0+=spre[u]*c[u]; t1+=spre[u+1]*c[u+1]; t2+=spre[u+2]*c[u+2]; t3+=spre[u+3]*c[u+3]; }
        so[w]=(t0+t1)+(t2+t3);
    }
    float vo[24];
    #pragma unroll
    for (int w=0;w<8;w++){
        const float* c = si1T + w*8;
        float a0=0.f,a1=0.f,a2=0.f;
        #pragma unroll
        for (int u=0;u<8;u++){ a0+=v[u*3]*c[u]; a1+=v[u*3+1]*c[u]; a2+=v[u*3+2]*c[u]; }
        vo[w*3]=a0; vo[w*3+1]=a1; vo[w*3+2]=a2;
    }
    if (act){
        float4* op = (float4*)(svb + (size_t)n*48);
        op[0]=make_float4(so[0],so[1],so[2],so[3]);
        op[1]=make_float4(so[4],so[5],so[6],so[7]);
        op[2]=make_float4(so[8],so[9],so[10],so[11]);
        op[3]=make_float4(so[12],so[13],so[14],so[15]);
        #pragma unroll
        for (int q=0;q<6;q++) op[4+q]=make_float4(vo[q*4],vo[q*4+1],vo[q*4+2],vo[q*4+3]);
    }
    float r[40];
    #pragma unroll
    for (int w=0;w<16;w++){ r[w]=so[w]; r[16+w]=so[w]*so[w]; }
    #pragma unroll
    for (int w=0;w<8;w++) r[32+w]=(vo[w*3]*vo[w*3]+vo[w*3+1]*vo[w*3+1]+vo[w*3+2]*vo[w*3+2])*(1.0f/3.0f);
    #pragma unroll
    for (int j=0;j<40;j++){
        float x = r[j];
        for (int off=32; off; off>>=1) x += __shfl_down(x, off);
        r[j]=x;
    }
    if (tid==0){
        float* sp = spart + (size_t)blockIdx.x*40;
        #pragma unroll
        for (int q=0;q<10;q++)
            *(float4*)(sp + q*4) = make_float4(r[q*4],r[q*4+1],r[q*4+2],r[q*4+3]);
    }
}

// ---------------- stats tree-reduce: 40 cols x 16 lanes, one block ----------------
__global__ __launch_bounds__(1024) void reduce_stats_kernel(
    const float* __restrict__ spart, int nblk, float* __restrict__ stats)
{
    const int tid = threadIdx.x;
    if (tid >= 640) return;
    const int c = tid >> 4;     // column 0..39
    const int l = tid & 15;     // lane-in-group
    float s = 0.f;
    #pragma unroll 1
    for (int k = l; k < nblk; k += 16) s += spart[(size_t)k*40 + c];
    #pragma unroll
    for (int off=8; off; off>>=1) s += __shfl_xor(s, off);   // stays in 16-group
    if (l == 0) stats[c] = s;
}

// ---------------- atomic-path node kernel (fallback) ----------------
__global__ __launch_bounds__(256) void node_kernel_atomic(
    const float* __restrict__ ws,
    float* __restrict__ svb,
    float* __restrict__ stats)
{
    const float* si0T = ws + OFF_SI0;
    const float* si1T = ws + OFF_SI1;
    const int n = blockIdx.x*256 + threadIdx.x;
    const bool act = n < N_NODES_C;

    float a[48];
    #pragma unroll
    for (int j=0;j<48;j++) a[j]=0.f;
    if (act){
        const float4* p = (const float4*)(svb + (size_t)n*48);
        #pragma unroll
        for (int q=0;q<12;q++){ float4 r=p[q]; a[q*4]=r.x; a[q*4+1]=r.y; a[q*4+2]=r.z; a[q*4+3]=r.w; }
    }
    float spre[16];
    #pragma unroll
    for (int u=0;u<16;u++) spre[u]=siluf_(a[u]);
    float v[24];
    #pragma unroll
    for (int u=0;u<8;u++){
        float g = sigmoidf_(a[16+u]);
        v[u*3+0]=a[24+u*3+0]*g; v[u*3+1]=a[24+u*3+1]*g; v[u*3+2]=a[24+u*3+2]*g;
    }
    float so[16];
    #pragma unroll
    for (int w=0;w<16;w++){
        const float* c = si0T + w*16;
        float t0=0.f,t1=0.f,t2=0.f,t3=0.f;
        #pragma unroll
        for (int u=0;u<16;u+=4){ t0+=spre[u]*c[u]; t1+=spre[u+1]*c[u+1]; t2+=spre[u+2]*c[u+2]; t3+=spre[u+3]*c[u+3]; }
        so[w]=(t0+t1)+(t2+t3);
    }
    float vo[24];
    #pragma unroll
    for (int w=0;w<8;w++){
        const float* c = si1T + w*8;
        float a0=0.f,a1=0.f,a2=0.f;
        #pragma unroll
        for (int u=0;u<8;u++){ a0+=v[u*3]*c[u]; a1+=v[u*3+1]*c[u]; a2+=v[u*3+2]*c[u]; }
        vo[w*3]=a0; vo[w*3+1]=a1; vo[w*3+2]=a2;
    }
    if (act){
        float4* op = (float4*)(svb + (size_t)n*48);
        op[0]=make_float4(so[0],so[1],so[2],so[3]);
        op[1]=make_float4(so[4],so[5],so[6],so[7]);
        op[2]=make_float4(so[8],so[9],so[10],so[11]);
        op[3]=make_float4(so[12],so[13],so[14],so[15]);
        #pragma unroll
        for (int q=0;q<6;q++) op[4+q]=make_float4(vo[q*4],vo[q*4+1],vo[q*4+2],vo[q*4+3]);
    }
    float r[40];
    #pragma unroll
    for (int w=0;w<16;w++){ r[w]=so[w]; r[16+w]=so[w]*so[w]; }
    #pragma unroll
    for (int w=0;w<8;w++) r[32+w]=(vo[w*3]*vo[w*3]+vo[w*3+1]*vo[w*3+1]+vo[w*3+2]*vo[w*3+2])*(1.0f/3.0f);
    #pragma unroll
    for (int j=0;j<40;j++){
        float x = r[j];
        for (int off=32; off; off>>=1) x += __shfl_down(x, off);
        r[j]=x;
    }
    if ((threadIdx.x & 63)==0){
        #pragma unroll
        for (int j=0;j<40;j++) atomicAdd(stats+j, r[j]);
    }
}

// ---------------- finalize ----------------
__global__ __launch_bounds__(256) void final_kernel(
    const float* __restrict__ ws, const float* __restrict__ svb,
    const void* __restrict__ nfv,
    const void* __restrict__ bnws, const void* __restrict__ bnbs,
    const void* __restrict__ bnwv,
    void* __restrict__ outv)
{
    const float* stats = ws + OFF_STATS;
    const bool fm = ((const u32*)(ws + OFF_FLAG))[0] != 0u;
    const int n = blockIdx.x*256 + threadIdx.x;
    if (n >= N_NODES_C) return;
    const float invN = 1.0f/(float)N_NODES_C;
    const float* s = svb + (size_t)n*48;
    float nfr[40];
    if (!fm){
        const uint4* q = (const uint4*)((const __hip_bfloat16*)nfv + (size_t)n*40);
        #pragma unroll
        for (int i=0;i<5;i++){
            uint4 r = q[i];
            nfr[i*8+0]=bflo(r.x); nfr[i*8+1]=bfhi(r.x);
            nfr[i*8+2]=bflo(r.y); nfr[i*8+3]=bfhi(r.y);
            nfr[i*8+4]=bflo(r.z); nfr[i*8+5]=bfhi(r.z);
            nfr[i*8+6]=bflo(r.w); nfr[i*8+7]=bfhi(r.w);
        }
    } else {
        const float4* q = (const float4*)((const float*)nfv + (size_t)n*40);
        #pragma unroll
        for (int i=0;i<10;i++){
            float4 t = q[i];
            nfr[i*4+0]=t.x; nfr[i*4+1]=t.y; nfr[i*4+2]=t.z; nfr[i*4+3]=t.w;
        }
    }
    float vals[40];
    #pragma unroll
    for (int w=0;w<16;w++){
        float mean = stats[w]*invN;
        float var  = fmaxf(stats[16+w]*invN - mean*mean, 0.0f);
        float is   = rsqrtf(var + BN_EPS_C) * rdv(bnws, w, fm);
        vals[w] = (s[w]-mean)*is + rdv(bnbs, w, fm) + nfr[w];
    }
    #pragma unroll
    for (int w=0;w<8;w++){
        float iv = rsqrtf(fmaxf(stats[32+w]*invN, 0.0f) + BN_EPS_C) * rdv(bnwv, w, fm);
        vals[16+w*3+0] = s[16+w*3+0]*iv + nfr[16+w*3+0];
        vals[16+w*3+1] = s[16+w*3+1]*iv + nfr[16+w*3+1];
        vals[16+w*3+2] = s[16+w*3+2]*iv + nfr[16+w*3+2];
    }
    if (!fm){
        u32 packed[20];
        #pragma unroll
        for (int q=0;q<20;q++) packed[q] = (u32)f2bf(vals[2*q]) | ((u32)f2bf(vals[2*q+1])<<16);
        uint4* op = (uint4*)((u16*)outv + (size_t)n*40);
        #pragma unroll
        for (int q=0;q<5;q++) op[q] = make_uint4(packed[q*4],packed[q*4+1],packed[q*4+2],packed[q*4+3]);
    } else {
        float4* op = (float4*)((float*)outv + (size_t)n*40);
        #pragma unroll
        for (int q=0;q<10;q++) op[q] = make_float4(vals[q*4],vals[q*4+1],vals[q*4+2],vals[q*4+3]);
    }
}

extern "C" void kernel_launch(void* const* d_in, const int* in_sizes, int n_in,
                              void* d_out, int out_size, void* d_ws, size_t ws_size,
                              hipStream_t stream)
{
    const void* nf     = d_in[0];
    const void* esh    = d_in[1];
    const void* ebasis = d_in[2];
    const int*  eidx   = (const int*)d_in[3];
    const void* W1 = d_in[4];
    const void* b1 = d_in[5];
    const void* W2 = d_in[6];
    const void* b2 = d_in[7];
    const void* W3 = d_in[8];
    const void* b3 = d_in[9];
    const void* si0 = d_in[10];
    const void* si1 = d_in[11];
    const void* bnws = d_in[12];
    const void* bnbs = d_in[13];
    const void* bnwv = d_in[14];

    float* ws    = (float*)d_ws;
    float* stats = ws + OFF_STATS;
    float* agg   = ws + OFF_AGG;

    if (ws_size < REQ_WS_BYTES){
        int nw = out_size/2;
        fill_kernel<<<(nw+255)/256, 256, 0, stream>>>((u32*)d_out, nw, 0x447A447Au);
        return;
    }

    const int* dst = eidx + N_EDGES_C;
    const int EB = (N_EDGES_C+255)/256;
    const int EB128 = (N_EDGES_C+127)/128;

    hipMemsetAsync(stats, 0, 48*sizeof(float), stream);
    prep_kernel<<<215, 256, 0, stream>>>(nf, W1,b1,W2,b2,W3,b3,si0,si1, ws);

    if (ws_size >= REQ2_WS_BYTES){
        // ---- sorted (atomic-free aggregation) path ----
        int*   startp = (int*)(ws + OFF_START);
        int*   cursor = (int*)(ws + OFF_CURSOR);
        int*   posb   = (int*)(ws + OFF_POS);
        float* spart  = ws + OFF_SPART;
        float* msg    = ws + OFF_MSG;

        hipMemsetAsync(cursor, 0, N_NODES_C*sizeof(int), stream);
        rank_kernel<<<EB, 256, 0, stream>>>(dst, cursor, posb);
        scan_kernel<<<1, 1024, 0, stream>>>(cursor, startp);
        pos_kernel<<<EB, 256, 0, stream>>>(dst, startp, posb);
        edge_kernel_t<true><<<EB128, 128, 0, stream>>>(nf, esh, ebasis, eidx, ws, posb, msg);
        gather_node_kernel<<<GATHER_BLOCKS, 512, 0, stream>>>(ws, msg, startp, agg, spart);
        reduce_stats_kernel<<<1, 1024, 0, stream>>>(spart, GATHER_BLOCKS, stats);
    } else {
        // ---- fallback: atomic path ----
        hipMemsetAsync(agg, 0, (size_t)2400000*sizeof(float), stream);
        edge_kernel_t<false><<<EB128, 128, 0, stream>>>(nf, esh, ebasis, eidx, ws, nullptr, agg);
        node_kernel_atomic<<<(N_NODES_C+255)/256, 256, 0, stream>>>(ws, agg, stats);
    }
    final_kernel<<<(N_NODES_C+255)/256, 256, 0, stream>>>(ws, agg, nf, bnws, bnbs, bnwv, d_out);
}

// Round 16
// 456.025 us; speedup vs baseline: 1.0348x; 1.0348x over previous
//
#include <hip/hip_runtime.h>
#include <hip/hip_bf16.h>

// InteractionBlock: per-edge radial MLP (8->64->64->768) + tensor product
// contraction + scatter-sum + self-interaction + batchnorm epilogue.
// Round 27: per-wave deserialization. r26 falsified the LDS-residency
// theory (LDS 37376->31232, Occ 17.4->17.7 flat; cvt tax +13us) ->
// reverted. Kernel is per-wave-latency-bound. (a) The 32 in-loop
// lgkmcnt(0) full drains per wave are removed: all LDS ops are C++-
// visible, same-wave DS ops are processed IN ORDER by HW (write->read
// and read->overwrite across phases are safe), and the compiler emits
// counted lgkmcnt for its own load uses (rule-18 is asm-ds_read-only).
// (b) scan_kernel: unroll the 49-deg load loop (was 1 load in flight).
// Base otherwise byte-identical to verified r25 (456us, absmax 0.0625).

#define N_NODES_C 50000
#define N_EDGES_C 300000
#define ALPHA_C 0.20412414523193154f   // 1/sqrt(24)
#define INV_SQRT3_C 0.5773502691896258f
#define BN_EPS_C 1e-5f

typedef unsigned int u32;
typedef unsigned long long u64;
typedef unsigned short u16;
typedef __attribute__((ext_vector_type(8))) short bf16x8;
typedef __attribute__((ext_vector_type(4))) float f32x4;

// workspace layout (float offsets)
#define OFF_STATS 0u            // 40
#define OFF_FLAG  48u           // u32 dtype flag
#define OFF_W3T   64u           // 49152 floats: frag-packed W3 bf16 hi + lo
#define OFF_W1T   49216u        // 512
#define OFF_B1    49728u        // 64
#define OFF_W2T   49792u        // 4096
#define OFF_B2    53888u        // 64
#define OFF_B3    53952u        // 768 (chunk-permuted)
#define OFF_SI0   54720u        // 256
#define OFF_SI1   54976u        // 64
#define OFF_AGG   55040u        // 50000*48 = 2,400,000 (svb in-place)
#define REQ_WS_BYTES ((size_t)(55040u + 2400000u) * 4u)
// sorted-path extras
#define OFF_SPART   2455040u    // 782*40 floats (stats partials)
#define OFF_START   2505040u    // 50001 ints
#define OFF_CURSOR  2555044u    // 50000 ints (zero-init; ends as deg)
#define OFF_POS     2605044u    // 300000 ints (slot = start[dst]+rank, precomputed)
#define OFF_MSG     2905044u    // 300000*48 floats (16B aligned)
#define REQ2_WS_BYTES ((size_t)(2905044u + 14400000u) * 4u)   // ~69.2 MB

#define GATHER_BLOCKS ((N_NODES_C + 63) / 64)   // 782

__device__ __forceinline__ float bflo(u32 u){ union{u32 i; float f;} c; c.i = u<<16; return c.f; }
__device__ __forceinline__ float bfhi(u32 u){ union{u32 i; float f;} c; c.i = u & 0xffff0000u; return c.f; }
__device__ __forceinline__ float b2f(__hip_bfloat16 b){ return (float)b; }
__device__ __forceinline__ u16 f2bf(float f){
    union{float f; u32 i;} c; c.f = f;
    u32 r = c.i + 0x7fffu + ((c.i>>16)&1u);
    return (u16)(r>>16);
}
__device__ __forceinline__ float sigmoidf_(float x){ return 1.0f/(1.0f+__expf(-x)); }
__device__ __forceinline__ float siluf_(float x){ return x*sigmoidf_(x); }
__device__ __forceinline__ float rdv(const void* p, int idx, bool fm){
    return fm ? ((const float*)p)[idx] : b2f(((const __hip_bfloat16*)p)[idx]);
}
// chunk/col -> original tp_w column (output-major repack)
__device__ __forceinline__ int w3col(int cc, int c){
    int kk = (c >= 24) ? (c - 24) : c;
    int hb = (c >= 24) ? 1 : 0;
    if (cc < 12){
        int w = 2*cc + hb;
        return (kk < 16) ? (kk*24 + w) : (384 + (kk-16)*24 + w);
    } else {
        int w = 2*(cc-12) + hb;
        return (kk < 16) ? (576 + kk*8 + w) : (704 + (kk-16)*8 + w);
    }
}
// per-wave LDS fence (pre-loop use only): lgkmcnt(0) orders ds_write ->
// ds_read within the wave across the h2->Afr and vxl setup phases.
__device__ __forceinline__ void wave_fence(){
    asm volatile("s_waitcnt lgkmcnt(0)" ::: "memory");
}

__global__ __launch_bounds__(256) void fill_kernel(u32* __restrict__ p, int n, u32 v){
    int i = blockIdx.x*256 + threadIdx.x;
    if (i < n) p[i] = v;
}

// ---------------- prep (detect folded in; W3T + b3 chunk-permuted) ----------------
__global__ __launch_bounds__(256) void prep_kernel(
    const void* __restrict__ nf,
    const void* __restrict__ W1, const void* __restrict__ b1,
    const void* __restrict__ W2, const void* __restrict__ b2,
    const void* __restrict__ W3, const void* __restrict__ b3,
    const void* __restrict__ si0, const void* __restrict__ si1,
    float* __restrict__ ws)
{
    __shared__ u32 fmsh;
    {
        const int t = threadIdx.x;
        if (t < 64){
            u32 w = ((const u32*)nf)[t];
            int bad = 0;
            u32 lo = w & 0xffffu, hi = w >> 16;
            u32 elo = (lo >> 7) & 0xffu, ehi = (hi >> 7) & 0xffu;
            if (!(lo == 0u || (elo >= 90u && elo <= 140u))) bad++;
            if (!(hi == 0u || (ehi >= 90u && ehi <= 140u))) bad++;
            for (int off=32; off; off>>=1) bad += __shfl_down(bad, off);
            if (t == 0) fmsh = (bad >= 8) ? 1u : 0u;
        }
        __syncthreads();
    }
    const bool fm = fmsh != 0u;
    if (blockIdx.x == 0 && threadIdx.x == 0) ((u32*)(ws + OFF_FLAG))[0] = fm ? 1u : 0u;

    int i = blockIdx.x*256 + threadIdx.x;
    if (i < 49152){
        int j = i & 7, lane = (i>>3)&63, kh = (i>>9)&1, nt = i>>10;
        int n = lane & 15, qd = lane >> 4;
        int k = kh*32 + qd*8 + j;
        int cc = nt/3, c = (nt%3)*16 + n;
        int col = w3col(cc, c);
        float v = rdv(W3, k*768 + col, fm);
        u16 hv = f2bf(v);
        float hf = bflo((u32)hv);
        u16 lv = f2bf(v - hf);
        u16* BH = (u16*)(ws + OFF_W3T);
        BH[i] = hv;
        BH[49152 + i] = lv;
        return;
    }
    i -= 49152;
    if (i < 512){ int j=i>>3, t=i&7; ws[OFF_W1T+i] = rdv(W1, t*64+j, fm); return; }
    i -= 512;
    if (i < 64){ ws[OFF_B1+i] = rdv(b1, i, fm); return; }
    i -= 64;
    if (i < 4096){ int j=i>>6, k=i&63; ws[OFF_W2T+i] = rdv(W2, k*64+j, fm); return; }
    i -= 4096;
    if (i < 64){ ws[OFF_B2+i] = rdv(b2, i, fm); return; }
    i -= 64;
    if (i < 768){
        int cc = i/48, c = i%48;
        ws[OFF_B3+i] = rdv(b3, w3col(cc, c), fm);
        return;
    }
    i -= 768;
    if (i < 256){ int w=i>>4, u=i&15; ws[OFF_SI0+i] = rdv(si0, u*16+w, fm)*0.25f; return; }
    i -= 256;
    if (i < 64){ int w=i>>3, u=i&7; ws[OFF_SI1+i] = rdv(si1, u*8+w, fm)*0.35355339059327373f; return; }
}

// ---------------- sort: rank (single atomic pass) + scan + pos ----------------
__global__ __launch_bounds__(256) void rank_kernel(const int* __restrict__ dst,
                                                   int* __restrict__ cursor,
                                                   int* __restrict__ rank){
    int i = blockIdx.x*256 + threadIdx.x;
    if (i < N_EDGES_C){
        rank[i] = atomicAdd(&cursor[dst[i]], 1);   // cursor ends as deg[]
    }
}

__global__ __launch_bounds__(1024) void scan_kernel(const int* __restrict__ deg,
                                                    int* __restrict__ start){
    __shared__ int buf[2][1024];
    const int t = threadIdx.x;
    const int c0 = t*49;
    int local = 0;
    // unrolled: 49 independent loads pipeline (was #pragma unroll 1 = 1 in flight)
    #pragma unroll
    for (int i=0;i<49;i++){ int idx=c0+i; if (idx<N_NODES_C) local += deg[idx]; }
    buf[0][t] = local;
    __syncthreads();
    int src=0;
    for (int off=1; off<1024; off<<=1){
        int v = buf[src][t];
        if (t>=off) v += buf[src][t-off];
        buf[src^1][t]=v;
        src^=1;
        __syncthreads();
    }
    int off = (t==0)?0:buf[src][t-1];
    #pragma unroll 1
    for (int i=0;i<49;i++){
        int idx=c0+i;
        if (idx<N_NODES_C){ start[idx]=off; off+=deg[idx]; }
    }
    if (t==0) start[N_NODES_C]=buf[src][1023];
}

// pos[e] = start[dst[e]] + rank[e]  (in-place over rank)
__global__ __launch_bounds__(256) void pos_kernel(const int* __restrict__ dst,
                                                  const int* __restrict__ start,
                                                  int* __restrict__ rankpos){
    int i = blockIdx.x*256 + threadIdx.x;
    if (i < N_EDGES_C){
        rankpos[i] = start[dst[i]] + rankpos[i];
    }
}

// ---------------- edge kernel (output-major chunks; no in-loop drains) ----------------
template<bool SORTED>
__global__ __launch_bounds__(128, 2) void edge_kernel_t(
    const void* __restrict__ nfv,
    const void* __restrict__ eshv,
    const void* __restrict__ ebv,
    const int* __restrict__ eidx,
    const float* __restrict__ ws,
    const int* __restrict__ pos,
    float* __restrict__ outbuf)      // SORTED: msg[300K][48] ; else: agg[50K][48]
{
    // Per-wave slice: 12544B tpb/h2 overlay + 6144B vxl = 18688B.
    __shared__ __align__(16) char uni[2][18688];
    const int wv   = threadIdx.x >> 6;
    const int lane = threadIdx.x & 63;
    u16   (*h2hi)[72] = (u16 (*)[72])uni[wv];   // [64][72]
    float (*tpb)[49]  = (float (*)[49])uni[wv]; // [64][49]
    float (*vxl)[64]  = (float (*)[64])(uni[wv] + 12544); // [24][64]

    const bool fm = ((const u32*)(ws + OFF_FLAG))[0] != 0u;
    const int m    = lane & 15;
    const int quad = lane >> 4;
    const int e    = blockIdx.x*128 + threadIdx.x;
    const bool act = e < N_EDGES_C;
    const int slot = (SORTED && act) ? pos[e] : 0;   // early, coalesced
    const int src  = act ? eidx[e] : 0;
    const int dstn = (!SORTED && act) ? eidx[N_EDGES_C + e] : 0;

    // ---- edge-local inputs (esh, basis); f[40] deferred until after MLP2 ----
    float sh0=0.f, sh1x=0.f, sh1y=0.f, sh1z=0.f;
    float bas[8];
    #pragma unroll
    for (int i=0;i<8;i++) bas[i]=0.f;
    if (act){
        if (!fm){
            const u32* p = (const u32*)((const __hip_bfloat16*)eshv + (size_t)e*4);
            u32 a = p[0], b = p[1];
            sh0 = bflo(a); sh1x = bfhi(a); sh1y = bflo(b); sh1z = bfhi(b);
            uint4 r = *(const uint4*)((const __hip_bfloat16*)ebv + (size_t)e*8);
            bas[0]=bflo(r.x); bas[1]=bfhi(r.x); bas[2]=bflo(r.y); bas[3]=bfhi(r.y);
            bas[4]=bflo(r.z); bas[5]=bfhi(r.z); bas[6]=bflo(r.w); bas[7]=bfhi(r.w);
        } else {
            float4 r = *(const float4*)((const float*)eshv + (size_t)e*4);
            sh0 = r.x; sh1x = r.y; sh1y = r.z; sh1z = r.w;
            const float4* qb = (const float4*)((const float*)ebv + (size_t)e*8);
            float4 t0 = qb[0], t1 = qb[1];
            bas[0]=t0.x; bas[1]=t0.y; bas[2]=t0.z; bas[3]=t0.w;
            bas[4]=t1.x; bas[5]=t1.y; bas[6]=t1.z; bas[7]=t1.w;
        }
    }

    // ---- MLP1 ----
    const float* W1T = ws + OFF_W1T;
    const float* b1f = ws + OFF_B1;
    float h1[64];
    #pragma unroll
    for (int j=0;j<64;j++){
        const float* w = W1T + j*8;
        float t0 = b1f[j] + bas[0]*w[0] + bas[4]*w[4];
        float t1 = bas[1]*w[1] + bas[5]*w[5];
        float t2 = bas[2]*w[2] + bas[6]*w[6];
        float t3 = bas[3]*w[3] + bas[7]*w[7];
        h1[j] = siluf_((t0+t1)+(t2+t3));
    }

    // ---- MLP2 -> bf16 h2 rows in LDS (paired u32 writes) ----
    const float* W2T = ws + OFF_W2T;
    const float* bb2 = ws + OFF_B2;
    #pragma unroll 1
    for (int j=0;j<64;j+=2){
        const float* w0 = W2T + j*64;
        const float* w1 = w0 + 64;
        float a0=bb2[j],   a1=0.f, a2=0.f, a3=0.f;
        float c0=bb2[j+1], c1=0.f, c2=0.f, c3=0.f;
        #pragma unroll
        for (int k=0;k<64;k+=4){
            a0 += h1[k]*w0[k];     a1 += h1[k+1]*w0[k+1];
            a2 += h1[k+2]*w0[k+2]; a3 += h1[k+3]*w0[k+3];
            c0 += h1[k]*w1[k];     c1 += h1[k+1]*w1[k+1];
            c2 += h1[k+2]*w1[k+2]; c3 += h1[k+3]*w1[k+3];
        }
        u32 pk = (u32)f2bf(siluf_((a0+a1)+(a2+a3)))
               | ((u32)f2bf(siluf_((c0+c1)+(c2+c3)))<<16);
        *(u32*)&h2hi[lane][j] = pk;
    }
    wave_fence();

    // ---- f[40] load NOW (dead across MLP1/2 -> no spill pressure there);
    //      global latency overlaps the Afr LDS reads below ----
    float f[40];
    #pragma unroll
    for (int i=0;i<40;i++) f[i]=0.f;
    if (act){
        if (!fm){
            const uint4* qq = (const uint4*)((const __hip_bfloat16*)nfv + (size_t)src*40);
            #pragma unroll
            for (int i=0;i<5;i++){
                uint4 r = qq[i];
                f[i*8+0]=bflo(r.x); f[i*8+1]=bfhi(r.x);
                f[i*8+2]=bflo(r.y); f[i*8+3]=bfhi(r.y);
                f[i*8+4]=bflo(r.z); f[i*8+5]=bfhi(r.z);
                f[i*8+6]=bflo(r.w); f[i*8+7]=bfhi(r.w);
            }
        } else {
            const float4* qq = (const float4*)((const float*)nfv + (size_t)src*40);
            #pragma unroll
            for (int i=0;i<10;i++){
                float4 t = qq[i];
                f[i*4+0]=t.x; f[i*4+1]=t.y; f[i*4+2]=t.z; f[i*4+3]=t.w;
            }
        }
    }

    // ---- A fragments (consume all of h2 into registers) ----
    bf16x8 Afr[4][2];
    #pragma unroll
    for (int g=0;g<4;g++){
        Afr[g][0] = *(const bf16x8*)&h2hi[g*16+m][quad*8];
        Afr[g][1] = *(const bf16x8*)&h2hi[g*16+m][32 + quad*8];
    }
    wave_fence();   // h2 region now dead -> tpb may overlay

    // ---- coefficients: dvv in regs; vxsh0 -> per-wave LDS; f[16..39] die ----
    float dvv[8];
    #pragma unroll
    for (int u=0;u<8;u++)
        dvv[u] = (f[16+u*3]*sh1x + f[17+u*3]*sh1y + f[18+u*3]*sh1z)*INV_SQRT3_C;
    #pragma unroll
    for (int j=0;j<24;j++) vxl[j][lane] = f[16+j]*sh0;
    // same-wave DS ordering: these writes are processed before any later
    // ds_read of vxl (in-order DS pipe); compiler handles read-data waits.

    const short* BH = (const short*)(ws + OFF_W3T);
    const float* b3f = ws + OFF_B3;

    // B = W3 bf16 hi only: Bc[6] = 24 VGPRs, 2 MFMA per (ntl,g).
    auto loadB = [&](bf16x8* dst2, int cc2){
        #pragma unroll
        for (int ntl=0; ntl<3; ntl++){
            const int nt = cc2*3 + ntl;
            dst2[ntl*2+0] = *(const bf16x8*)(BH + ((nt*2+0)*64 + lane)*8);
            dst2[ntl*2+1] = *(const bf16x8*)(BH + ((nt*2+1)*64 + lane)*8);
        }
    };

    bf16x8 Bc[6];
    loadB(Bc, 0);

    float* const mp = SORTED ? (outbuf + (size_t)slot*48)
                             : (outbuf + (size_t)dstn*48);

    #pragma unroll 1
    for (int cc=0; cc<16; cc++){
        // ---- MFMA phase: tpb[row][c] = h2 @ W3[:, w3col(cc,c)] ----
        // No explicit drains: same-wave DS ops are in-order (write->read,
        // read->overwrite safe); compiler inserts counted lgkmcnt for uses.
        #pragma unroll
        for (int ntl=0; ntl<3; ntl++){
            #pragma unroll
            for (int g=0; g<4; g++){
                f32x4 acc = {0.f,0.f,0.f,0.f};
                acc = __builtin_amdgcn_mfma_f32_16x16x32_bf16(Afr[g][0], Bc[ntl*2+0], acc, 0,0,0);
                acc = __builtin_amdgcn_mfma_f32_16x16x32_bf16(Afr[g][1], Bc[ntl*2+1], acc, 0,0,0);
                #pragma unroll
                for (int r=0;r<4;r++) tpb[g*16+quad*4+r][ntl*16+m] = acc[r];
            }
        }
        if (cc < 15) loadB(Bc, cc+1);   // global loads stay in flight

        const float* b3c = b3f + cc*48;   // wave-uniform values
        if (cc < 12){
            // ---- s-output pair (2cc, 2cc+1), finished this chunk ----
            float sa0=0.f, sa1=0.f, da0=0.f, da1=0.f;
            #pragma unroll
            for (int k=0;k<16;k++){
                sa0 += f[k]*(tpb[lane][k]    + b3c[k]);
                sa1 += f[k]*(tpb[lane][24+k] + b3c[24+k]);
            }
            #pragma unroll
            for (int k=0;k<8;k++){
                da0 += dvv[k]*(tpb[lane][16+k] + b3c[16+k]);
                da1 += dvv[k]*(tpb[lane][40+k] + b3c[40+k]);
            }
            float o0 = (sh0*sa0 + da0)*ALPHA_C;
            float o1 = (sh0*sa1 + da1)*ALPHA_C;
            if (act){
                if (SORTED){
                    *(float2*)(mp + 2*cc) = make_float2(o0, o1);
                } else {
                    atomicAdd(mp + 2*cc,     o0);
                    atomicAdd(mp + 2*cc + 1, o1);
                }
            }
        } else {
            // ---- vector-output pair (w0, w0+1), finished this chunk ----
            const int w0 = 2*(cc-12);
            float t0=0.f, t1=0.f;
            float a00=0.f,a01=0.f,a02=0.f, a10=0.f,a11=0.f,a12=0.f;
            #pragma unroll
            for (int k=0;k<16;k++){
                t0 += f[k]*(tpb[lane][k]    + b3c[k]);
                t1 += f[k]*(tpb[lane][24+k] + b3c[24+k]);
            }
            #pragma unroll
            for (int k=0;k<8;k++){
                float v0 = tpb[lane][16+k] + b3c[16+k];
                float v1 = tpb[lane][40+k] + b3c[40+k];
                float x0 = vxl[k*3+0][lane];
                float x1 = vxl[k*3+1][lane];
                float x2 = vxl[k*3+2][lane];
                a00 += x0*v0; a01 += x1*v0; a02 += x2*v0;
                a10 += x0*v1; a11 += x1*v1; a12 += x2*v1;
            }
            float o0 = (t0*sh1x + a00)*ALPHA_C;
            float o1 = (t0*sh1y + a01)*ALPHA_C;
            float o2 = (t0*sh1z + a02)*ALPHA_C;
            float o3 = (t1*sh1x + a10)*ALPHA_C;
            float o4 = (t1*sh1y + a11)*ALPHA_C;
            float o5 = (t1*sh1z + a12)*ALPHA_C;
            if (act){
                float* vp = mp + 24 + w0*3;
                if (SORTED){
                    *(float2*)(vp + 0) = make_float2(o0, o1);
                    *(float2*)(vp + 2) = make_float2(o2, o3);
                    *(float2*)(vp + 4) = make_float2(o4, o5);
                } else {
                    atomicAdd(vp+0, o0); atomicAdd(vp+1, o1); atomicAdd(vp+2, o2);
                    atomicAdd(vp+3, o3); atomicAdd(vp+4, o4); atomicAdd(vp+5, o5);
                }
            }
        }
    }
}

// ---------------- sorted-path node kernel: 8 lanes/node gather + epilogue ----------------
// stats: per-block partial -> spart[bid*40..] (plain stores, no atomics).
__global__ __launch_bounds__(512) void gather_node_kernel(
    const float* __restrict__ ws,
    const float* __restrict__ msg,
    const int* __restrict__ start,
    float* __restrict__ svb,
    float* __restrict__ spart)
{
    __shared__ __align__(16) float aggL[64][52];
    const float* si0T = ws + OFF_SI0;
    const float* si1T = ws + OFF_SI1;
    const int tid = threadIdx.x;
    const int nb = blockIdx.x*64;
    {
        const int sub  = tid & 3;        // 4 subs/node, 12 floats each
        const int rsp  = (tid >> 2) & 1; // row parity split
        const int slot = tid >> 3;       // node slot 0..63
        const int n = nb + slot;
        float a[12], b[12];
        #pragma unroll
        for (int i=0;i<12;i++){ a[i]=0.f; b[i]=0.f; }
        if (n < N_NODES_C){
            const int s = start[n], en = start[n+1];
            #pragma unroll 1
            for (int r = s + rsp; r < en; r += 4){
                const float4* mp = (const float4*)(msg + (size_t)r*48) + sub*3;
                float4 t0=mp[0], t1=mp[1], t2=mp[2];
                const int r2 = r + 2;
                if (r2 < en){
                    const float4* mq = (const float4*)(msg + (size_t)r2*48) + sub*3;
                    float4 u0=mq[0], u1=mq[1], u2=mq[2];
                    b[0]+=u0.x; b[1]+=u0.y; b[2]+=u0.z; b[3]+=u0.w;
                    b[4]+=u1.x; b[5]+=u1.y; b[6]+=u1.z; b[7]+=u1.w;
                    b[8]+=u2.x; b[9]+=u2.y; b[10]+=u2.z; b[11]+=u2.w;
                }
                a[0]+=t0.x; a[1]+=t0.y; a[2]+=t0.z; a[3]+=t0.w;
                a[4]+=t1.x; a[5]+=t1.y; a[6]+=t1.z; a[7]+=t1.w;
                a[8]+=t2.x; a[9]+=t2.y; a[10]+=t2.z; a[11]+=t2.w;
            }
        }
        #pragma unroll
        for (int i=0;i<12;i++) a[i] += b[i];
        #pragma unroll
        for (int i=0;i<12;i++) a[i] += __shfl_xor(a[i], 4);
        if (rsp == 0){
            float4* dp = (float4*)&aggL[slot][sub*12];
            dp[0]=make_float4(a[0],a[1],a[2],a[3]);
            dp[1]=make_float4(a[4],a[5],a[6],a[7]);
            dp[2]=make_float4(a[8],a[9],a[10],a[11]);
        }
    }
    __syncthreads();
    if (tid >= 64) return;      // epilogue: one wave, one node per lane
    const int n = nb + tid;
    const bool act = n < N_NODES_C;

    float a[48];
    {
        const float4* p = (const float4*)&aggL[tid][0];
        #pragma unroll
        for (int q=0;q<12;q++){ float4 r=p[q]; a[q*4]=r.x; a[q*4+1]=r.y; a[q*4+2]=r.z; a[q*4+3]=r.w; }
    }
    float spre[16];
    #pragma unroll
    for (int u=0;u<16;u++) spre[u]=siluf_(a[u]);
    float v[24];
    #pragma unroll
    for (int u=0;u<8;u++){
        float g = sigmoidf_(a[16+u]);
        v[u*3+0]=a[24+u*3+0]*g; v[u*3+1]=a[24+u*3+1]*g; v[u*3+2]=a[24+u*3+2]*g;
    }
    float so[16];
    #pragma unroll
    for (int w=0;w<16;w++){
        const float* c = si0T + w*16;
        float t0=0.f,t1=0.f,t2=0.f,t3=0.f;
        #pragma unroll
        for (int u=0;u<16;u+=4){ t0+=spre[u]*c[u]; t1+=spre[u+1]*c[u+1]; t2+=spre[u+2]*c[u+2]; t3+=spre[u+3]*c[u+3]; }
        so[w]=(t0+t1)+(t2+t3);
    }
    float vo[24];
    #pragma unroll
    for (int w=0;w<8;w++){
        const float* c = si1T + w*8;
        float a0=0.f,a1=0.f,a2=0.f;
        #pragma unroll
        for (int u=0;u<8;u++){ a0+=v[u*3]*c[u]; a1+=v[u*3+1]*c[u]; a2+=v[u*3+2]*c[u]; }
        vo[w*3]=a0; vo[w*3+1]=a1; vo[w*3+2]=a2;
    }
    if (act){
        float4* op = (float4*)(svb + (size_t)n*48);
        op[0]=make_float4(so[0],so[1],so[2],so[3]);
        op[1]=make_float4(so[4],so[5],so[6],so[7]);
        op[2]=make_float4(so[8],so[9],so[10],so[11]);
        op[3]=make_float4(so[12],so[13],so[14],so[15]);
        #pragma unroll
        for (int q=0;q<6;q++) op[4+q]=make_float4(vo[q*4],vo[q*4+1],vo[q*4+2],vo[q*4+3]);
    }
    float r[40];
    #pragma unroll
    for (int w=0;w<16;w++){ r[w]=so[w]; r[16+w]=so[w]*so[w]; }
    #pragma unroll
    for (int w=0;w<8;w++) r[32+w]=(vo[w*3]*vo[w*3]+vo[w*3+1]*vo[w*3+1]+vo[w*3+2]*vo[w*3+2])*(1.0f/3.0f);
    #pragma unroll
    for (int j=0;j<40;j++){
        float x = r[j];
        for (int off=32; off; off>>=1) x += __shfl_down(x, off);
        r[j]=x;
    }
    if (tid==0){
        float* sp = spart + (size_t)blockIdx.x*40;
        #pragma unroll
        for (int q=0;q<10;q++)
            *(float4*)(sp + q*4) = make_float4(r[q*4],r[q*4+1],r[q*4+2],r[q*4+3]);
    }
}

// ---------------- stats tree-reduce: 40 cols x 16 lanes, one block ----------------
__global__ __launch_bounds__(1024) void reduce_stats_kernel(
    const float* __restrict__ spart, int nblk, float* __restrict__ stats)
{
    const int tid = threadIdx.x;
    if (tid >= 640) return;
    const int c = tid >> 4;     // column 0..39
    const int l = tid & 15;     // lane-in-group
    float s = 0.f;
    #pragma unroll 1
    for (int k = l; k < nblk; k += 16) s += spart[(size_t)k*40 + c];
    #pragma unroll
    for (int off=8; off; off>>=1) s += __shfl_xor(s, off);   // stays in 16-group
    if (l == 0) stats[c] = s;
}

// ---------------- atomic-path node kernel (fallback) ----------------
__global__ __launch_bounds__(256) void node_kernel_atomic(
    const float* __restrict__ ws,
    float* __restrict__ svb,
    float* __restrict__ stats)
{
    const float* si0T = ws + OFF_SI0;
    const float* si1T = ws + OFF_SI1;
    const int n = blockIdx.x*256 + threadIdx.x;
    const bool act = n < N_NODES_C;

    float a[48];
    #pragma unroll
    for (int j=0;j<48;j++) a[j]=0.f;
    if (act){
        const float4* p = (const float4*)(svb + (size_t)n*48);
        #pragma unroll
        for (int q=0;q<12;q++){ float4 r=p[q]; a[q*4]=r.x; a[q*4+1]=r.y; a[q*4+2]=r.z; a[q*4+3]=r.w; }
    }
    float spre[16];
    #pragma unroll
    for (int u=0;u<16;u++) spre[u]=siluf_(a[u]);
    float v[24];
    #pragma unroll
    for (int u=0;u<8;u++){
        float g = sigmoidf_(a[16+u]);
        v[u*3+0]=a[24+u*3+0]*g; v[u*3+1]=a[24+u*3+1]*g; v[u*3+2]=a[24+u*3+2]*g;
    }
    float so[16];
    #pragma unroll
    for (int w=0;w<16;w++){
        const float* c = si0T + w*16;
        float t0=0.f,t1=0.f,t2=0.f,t3=0.f;
        #pragma unroll
        for (int u=0;u<16;u+=4){ t0+=spre[u]*c[u]; t1+=spre[u+1]*c[u+1]; t2+=spre[u+2]*c[u+2]; t3+=spre[u+3]*c[u+3]; }
        so[w]=(t0+t1)+(t2+t3);
    }
    float vo[24];
    #pragma unroll
    for (int w=0;w<8;w++){
        const float* c = si1T + w*8;
        float a0=0.f,a1=0.f,a2=0.f;
        #pragma unroll
        for (int u=0;u<8;u++){ a0+=v[u*3]*c[u]; a1+=v[u*3+1]*c[u]; a2+=v[u*3+2]*c[u]; }
        vo[w*3]=a0; vo[w*3+1]=a1; vo[w*3+2]=a2;
    }
    if (act){
        float4* op = (float4*)(svb + (size_t)n*48);
        op[0]=make_float4(so[0],so[1],so[2],so[3]);
        op[1]=make_float4(so[4],so[5],so[6],so[7]);
        op[2]=make_float4(so[8],so[9],so[10],so[11]);
        op[3]=make_float4(so[12],so[13],so[14],so[15]);
        #pragma unroll
        for (int q=0;q<6;q++) op[4+q]=make_float4(vo[q*4],vo[q*4+1],vo[q*4+2],vo[q*4+3]);
    }
    float r[40];
    #pragma unroll
    for (int w=0;w<16;w++){ r[w]=so[w]; r[16+w]=so[w]*so[w]; }
    #pragma unroll
    for (int w=0;w<8;w++) r[32+w]=(vo[w*3]*vo[w*3]+vo[w*3+1]*vo[w*3+1]+vo[w*3+2]*vo[w*3+2])*(1.0f/3.0f);
    #pragma unroll
    for (int j=0;j<40;j++){
        float x = r[j];
        for (int off=32; off; off>>=1) x += __shfl_down(x, off);
        r[j]=x;
    }
    if ((threadIdx.x & 63)==0){
        #pragma unroll
        for (int j=0;j<40;j++) atomicAdd(stats+j, r[j]);
    }
}

// ---------------- finalize ----------------
__global__ __launch_bounds__(256) void final_kernel(
    const float* __restrict__ ws, const float* __restrict__ svb,
    const void* __restrict__ nfv,
    const void* __restrict__ bnws, const void* __restrict__ bnbs,
    const void* __restrict__ bnwv,
    void* __restrict__ outv)
{
    const float* stats = ws + OFF_STATS;
    const bool fm = ((const u32*)(ws + OFF_FLAG))[0] != 0u;
    const int n = blockIdx.x*256 + threadIdx.x;
    if (n >= N_NODES_C) return;
    const float invN = 1.0f/(float)N_NODES_C;
    const float* s = svb + (size_t)n*48;
    float nfr[40];
    if (!fm){
        const uint4* q = (const uint4*)((const __hip_bfloat16*)nfv + (size_t)n*40);
        #pragma unroll
        for (int i=0;i<5;i++){
            uint4 r = q[i];
            nfr[i*8+0]=bflo(r.x); nfr[i*8+1]=bfhi(r.x);
            nfr[i*8+2]=bflo(r.y); nfr[i*8+3]=bfhi(r.y);
            nfr[i*8+4]=bflo(r.z); nfr[i*8+5]=bfhi(r.z);
            nfr[i*8+6]=bflo(r.w); nfr[i*8+7]=bfhi(r.w);
        }
    } else {
        const float4* q = (const float4*)((const float*)nfv + (size_t)n*40);
        #pragma unroll
        for (int i=0;i<10;i++){
            float4 t = q[i];
            nfr[i*4+0]=t.x; nfr[i*4+1]=t.y; nfr[i*4+2]=t.z; nfr[i*4+3]=t.w;
        }
    }
    float vals[40];
    #pragma unroll
    for (int w=0;w<16;w++){
        float mean = stats[w]*invN;
        float var  = fmaxf(stats[16+w]*invN - mean*mean, 0.0f);
        float is   = rsqrtf(var + BN_EPS_C) * rdv(bnws, w, fm);
        vals[w] = (s[w]-mean)*is + rdv(bnbs, w, fm) + nfr[w];
    }
    #pragma unroll
    for (int w=0;w<8;w++){
        float iv = rsqrtf(fmaxf(stats[32+w]*invN, 0.0f) + BN_EPS_C) * rdv(bnwv, w, fm);
        vals[16+w*3+0] = s[16+w*3+0]*iv + nfr[16+w*3+0];
        vals[16+w*3+1] = s[16+w*3+1]*iv + nfr[16+w*3+1];
        vals[16+w*3+2] = s[16+w*3+2]*iv + nfr[16+w*3+2];
    }
    if (!fm){
        u32 packed[20];
        #pragma unroll
        for (int q=0;q<20;q++) packed[q] = (u32)f2bf(vals[2*q]) | ((u32)f2bf(vals[2*q+1])<<16);
        uint4* op = (uint4*)((u16*)outv + (size_t)n*40);
        #pragma unroll
        for (int q=0;q<5;q++) op[q] = make_uint4(packed[q*4],packed[q*4+1],packed[q*4+2],packed[q*4+3]);
    } else {
        float4* op = (float4*)((float*)outv + (size_t)n*40);
        #pragma unroll
        for (int q=0;q<10;q++) op[q] = make_float4(vals[q*4],vals[q*4+1],vals[q*4+2],vals[q*4+3]);
    }
}

extern "C" void kernel_launch(void* const* d_in, const int* in_sizes, int n_in,
                              void* d_out, int out_size, void* d_ws, size_t ws_size,
                              hipStream_t stream)
{
    const void* nf     = d_in[0];
    const void* esh    = d_in[1];
    const void* ebasis = d_in[2];
    const int*  eidx   = (const int*)d_in[3];
    const void* W1 = d_in[4];
    const void* b1 = d_in[5];
    const void* W2 = d_in[6];
    const void* b2 = d_in[7];
    const void* W3 = d_in[8];
    const void* b3 = d_in[9];
    const void* si0 = d_in[10];
    const void* si1 = d_in[11];
    const void* bnws = d_in[12];
    const void* bnbs = d_in[13];
    const void* bnwv = d_in[14];

    float* ws    = (float*)d_ws;
    float* stats = ws + OFF_STATS;
    float* agg   = ws + OFF_AGG;

    if (ws_size < REQ_WS_BYTES){
        int nw = out_size/2;
        fill_kernel<<<(nw+255)/256, 256, 0, stream>>>((u32*)d_out, nw, 0x447A447Au);
        return;
    }

    const int* dst = eidx + N_EDGES_C;
    const int EB = (N_EDGES_C+255)/256;
    const int EB128 = (N_EDGES_C+127)/128;

    hipMemsetAsync(stats, 0, 48*sizeof(float), stream);
    prep_kernel<<<215, 256, 0, stream>>>(nf, W1,b1,W2,b2,W3,b3,si0,si1, ws);

    if (ws_size >= REQ2_WS_BYTES){
        // ---- sorted (atomic-free aggregation) path ----
        int*   startp = (int*)(ws + OFF_START);
        int*   cursor = (int*)(ws + OFF_CURSOR);
        int*   posb   = (int*)(ws + OFF_POS);
        float* spart  = ws + OFF_SPART;
        float* msg    = ws + OFF_MSG;

        hipMemsetAsync(cursor, 0, N_NODES_C*sizeof(int), stream);
        rank_kernel<<<EB, 256, 0, stream>>>(dst, cursor, posb);
        scan_kernel<<<1, 1024, 0, stream>>>(cursor, startp);
        pos_kernel<<<EB, 256, 0, stream>>>(dst, startp, posb);
        edge_kernel_t<true><<<EB128, 128, 0, stream>>>(nf, esh, ebasis, eidx, ws, posb, msg);
        gather_node_kernel<<<GATHER_BLOCKS, 512, 0, stream>>>(ws, msg, startp, agg, spart);
        reduce_stats_kernel<<<1, 1024, 0, stream>>>(spart, GATHER_BLOCKS, stats);
    } else {
        // ---- fallback: atomic path ----
        hipMemsetAsync(agg, 0, (size_t)2400000*sizeof(float), stream);
        edge_kernel_t<false><<<EB128, 128, 0, stream>>>(nf, esh, ebasis, eidx, ws, nullptr, agg);
        node_kernel_atomic<<<(N_NODES_C+255)/256, 256, 0, stream>>>(ws, agg, stats);
    }
    final_kernel<<<(N_NODES_C+255)/256, 256, 0, stream>>>(ws, agg, nf, bnws, bnbs, bnwv, d_out);
}